// Round 1
// baseline (429.301 us; speedup 1.0000x reference)
//
#include <hip/hip_runtime.h>
#include <math.h>

#define IN_CH 128
#define OUT_CH 64
#define NEG_SLOPE 0.2f

// ---------- K0: init per-node state ----------
__global__ void k_init(int* counts, unsigned* amaxb, int N) {
    int i = blockIdx.x * blockDim.x + threadIdx.x;
    if (i < N) {
        counts[i] = 1;      // self loop pre-counted
        amaxb[i]  = 0u;     // encoded -inf sentinel (any real enc value is > 0)
    }
}

// ---------- K1: edge dtype sniff + convert to int32 + degree count ----------
__global__ void k_conv(const void* __restrict__ edges, int* __restrict__ srcI,
                       int* __restrict__ dstI, int* __restrict__ counts, int E) {
    int e = blockIdx.x * blockDim.x + threadIdx.x;
    if (e >= E) return;
    // detect int64 vs int32 storage: int64 little-endian => odd int32 words are 0
    const unsigned* up = (const unsigned*)edges;
    bool is64 = true;
#pragma unroll
    for (int k = 0; k < 16; k++) is64 = is64 && (up[2 * k + 1] == 0u);
    int s, d;
    if (is64) {
        const long long* p = (const long long*)edges;
        s = (int)p[e];
        d = (int)p[(size_t)E + e];
    } else {
        const int* p = (const int*)edges;
        s = p[e];
        d = p[E + e];
    }
    srcI[e] = s;
    dstI[e] = d;
    atomicAdd(counts + d, 1);
}

// ---------- K2: h = x @ W, plus per-node attention dots ----------
__global__ __launch_bounds__(256) void k_mm(const float* __restrict__ x,
                                            const float* __restrict__ W,
                                            const float* __restrict__ att,
                                            float* __restrict__ h,
                                            float* __restrict__ asrc,
                                            float* __restrict__ adst, int N) {
    __shared__ float Ws[IN_CH * OUT_CH];   // 32 KB
    __shared__ float xS[8 * IN_CH];        // 4 KB: 8 nodes/block
    __shared__ float attS[2 * OUT_CH];
    int t = threadIdx.x;
    for (int i = t; i < IN_CH * OUT_CH; i += 256) Ws[i] = W[i];
    if (t < 2 * OUT_CH) attS[t] = att[t];
    // stage 8 node rows of x
    int base_node = blockIdx.x * 8;
    for (int i = t; i < 8 * IN_CH; i += 256) {
        int nn = base_node + (i >> 7);
        xS[i] = (nn < N) ? x[(size_t)nn * IN_CH + (i & 127)] : 0.f;
    }
    __syncthreads();
    int lane = t & 63, wave = t >> 6;
    for (int rep = 0; rep < 2; rep++) {
        int local = wave * 2 + rep;
        int node = base_node + local;
        if (node >= N) continue;
        float acc = 0.f;
        const float* xr = &xS[local * IN_CH];
#pragma unroll
        for (int k = 0; k < IN_CH; k++) acc = fmaf(xr[k], Ws[k * 64 + lane], acc);
        h[(size_t)node * 64 + lane] = acc;
        float pd = acc * attS[lane];        // dst side: att[0:64]
        float ps = acc * attS[64 + lane];   // src side: att[64:128]
#pragma unroll
        for (int m = 32; m >= 1; m >>= 1) {
            pd += __shfl_xor(pd, m, 64);
            ps += __shfl_xor(ps, m, 64);
        }
        if (lane == 0) { adst[node] = pd; asrc[node] = ps; }
    }
}

// ---------- K3: single-block scan of degrees -> rowptr + cursor ----------
__global__ __launch_bounds__(1024) void k_scan(const int* __restrict__ counts,
                                               int* __restrict__ rowptr,
                                               int* __restrict__ cursor, int N) {
    __shared__ int part[1024];
    int t = threadIdx.x;
    int C = (N + 1023) / 1024;
    int b = min(t * C, N), e = min(b + C, N);
    int s = 0;
    for (int i = b; i < e; i++) s += counts[i];
    part[t] = s;
    __syncthreads();
    for (int off = 1; off < 1024; off <<= 1) {
        int v = (t >= off) ? part[t - off] : 0;
        __syncthreads();
        part[t] += v;
        __syncthreads();
    }
    int run = (t == 0) ? 0 : part[t - 1];
    for (int i = b; i < e; i++) {
        rowptr[i] = run;
        cursor[i] = run;
        run += counts[i];
    }
    if (t == 1023) rowptr[N] = part[1023];
}

// ---------- K4: per-edge alpha, atomic segment-max, CSR scatter ----------
__global__ void k_edge(const int* __restrict__ srcI, const int* __restrict__ dstI,
                       const float* __restrict__ asrc, const float* __restrict__ adst,
                       unsigned* __restrict__ amaxb, int* __restrict__ cursor,
                       int* __restrict__ csr_src, float* __restrict__ csr_alpha,
                       int E, int N) {
    int e = blockIdx.x * blockDim.x + threadIdx.x;
    if (e >= E + N) return;
    int s, d;
    if (e < E) { s = srcI[e]; d = dstI[e]; }
    else       { s = d = e - E; }           // self loop
    float a = adst[d] + asrc[s];
    a = a > 0.f ? a : NEG_SLOPE * a;        // leaky relu
    unsigned u = __float_as_uint(a);
    unsigned enc = (u >> 31) ? ~u : (u | 0x80000000u);  // order-preserving map
    atomicMax(amaxb + d, enc);
    int pos = atomicAdd(cursor + d, 1);
    csr_src[pos] = s;
    csr_alpha[pos] = a;
}

// ---------- K5: per-node gather softmax-aggregate + bias + L2 normalize ----------
__global__ __launch_bounds__(256) void k_agg(const float* __restrict__ h,
                                             const float* __restrict__ csr_alpha,
                                             const int* __restrict__ csr_src,
                                             const int* __restrict__ rowptr,
                                             const unsigned* __restrict__ amaxb,
                                             const float* __restrict__ bias,
                                             float* __restrict__ out, int N) {
    int lane = threadIdx.x & 63;
    int node = blockIdx.x * 4 + (threadIdx.x >> 6);
    if (node >= N) return;
    unsigned u = amaxb[node];
    float amax = (u >> 31) ? __uint_as_float(u ^ 0x80000000u) : __uint_as_float(~u);
    int b0 = rowptr[node], b1 = rowptr[node + 1];
    float acc = 0.f, esum = 0.f;
    for (int p = b0; p < b1; p++) {
        int s = csr_src[p];               // wave-uniform broadcast load
        float w = __expf(csr_alpha[p] - amax);
        esum += w;
        acc = fmaf(w, h[(size_t)s * 64 + lane], acc);  // 256B coalesced gather
    }
    float val = acc / (esum + 1e-16f) + bias[lane];
    float ss = val * val;
#pragma unroll
    for (int m = 32; m >= 1; m >>= 1) ss += __shfl_xor(ss, m, 64);
    float nrm = fmaxf(sqrtf(ss), 1e-12f);
    out[(size_t)node * 64 + lane] = val / nrm;
}

extern "C" void kernel_launch(void* const* d_in, const int* in_sizes, int n_in,
                              void* d_out, int out_size, void* d_ws, size_t ws_size,
                              hipStream_t stream) {
    const float* x    = (const float*)d_in[0];
    const void*  edges = d_in[1];
    const float* W    = (const float*)d_in[2];
    const float* att  = (const float*)d_in[3];
    const float* bias = (const float*)d_in[4];
    float* out = (float*)d_out;

    const int N = in_sizes[0] / IN_CH;
    const int E = in_sizes[1] / 2;
    const int EN = E + N;

    char* ws = (char*)d_ws;
    size_t off = 0;
    auto alloc = [&](size_t bytes) -> void* {
        void* p = ws + off;
        off += bytes;
        off = (off + 255) & ~(size_t)255;
        return p;
    };
    int*      srcI      = (int*)alloc((size_t)E * 4);
    int*      dstI      = (int*)alloc((size_t)E * 4);
    int*      counts    = (int*)alloc((size_t)N * 4);
    int*      rowptr    = (int*)alloc((size_t)(N + 1) * 4);
    int*      cursor    = (int*)alloc((size_t)N * 4);
    unsigned* amaxb     = (unsigned*)alloc((size_t)N * 4);
    float*    h         = (float*)alloc((size_t)N * OUT_CH * 4);
    float*    asrc      = (float*)alloc((size_t)N * 4);
    float*    adst      = (float*)alloc((size_t)N * 4);
    int*      csr_src   = (int*)alloc((size_t)EN * 4);
    float*    csr_alpha = (float*)alloc((size_t)EN * 4);

    k_init<<<(N + 255) / 256, 256, 0, stream>>>(counts, amaxb, N);
    k_conv<<<(E + 255) / 256, 256, 0, stream>>>(edges, srcI, dstI, counts, E);
    k_mm<<<(N + 7) / 8, 256, 0, stream>>>(x, W, att, h, asrc, adst, N);
    k_scan<<<1, 1024, 0, stream>>>(counts, rowptr, cursor, N);
    k_edge<<<(EN + 255) / 256, 256, 0, stream>>>(srcI, dstI, asrc, adst, amaxb,
                                                 cursor, csr_src, csr_alpha, E, N);
    k_agg<<<(N + 3) / 4, 256, 0, stream>>>(h, csr_alpha, csr_src, rowptr, amaxb,
                                           bias, out, N);
}

// Round 2
// 253.340 us; speedup vs baseline: 1.6946x; 1.6946x over previous
//
#include <hip/hip_runtime.h>
#include <math.h>

#define IN_CH 128
#define OUT_CH 64
#define NEG_SLOPE 0.2f

// ---------- edge dtype sniff: int64 little-endian => odd int32 words are 0 ----------
__device__ __forceinline__ bool sniff_is64(const void* edges) {
    const unsigned* up = (const unsigned*)edges;
    bool is64 = true;
#pragma unroll
    for (int k = 0; k < 16; k++) is64 = is64 && (up[2 * k + 1] == 0u);
    return is64;
}

// ---------- K0: init degree counts (self loop pre-counted) ----------
__global__ void k_init(int* counts, int N) {
    int i = blockIdx.x * blockDim.x + threadIdx.x;
    if (i < N) counts[i] = 1;
}

// ---------- K1: degree count straight from edge_index ----------
__global__ void k_count(const void* __restrict__ edges, int* __restrict__ counts, int E) {
    int e = blockIdx.x * blockDim.x + threadIdx.x;
    if (e >= E) return;
    int d;
    if (sniff_is64(edges)) d = (int)((const long long*)edges)[(size_t)E + e];
    else                   d = ((const int*)edges)[E + e];
    atomicAdd(counts + d, 1);
}

// ---------- K2: h = x @ W + per-node attention dots ----------
// 256 threads: cg = t&15 (4 channels), g = t>>4 (4 nodes each) -> 64 nodes/block.
// W in LDS (b128 reads), x from global (float4, 16-lane broadcast merge).
__global__ __launch_bounds__(256) void k_mm(const float* __restrict__ x,
                                            const float* __restrict__ W,
                                            const float* __restrict__ att,
                                            float* __restrict__ h,
                                            float* __restrict__ asrc,
                                            float* __restrict__ adst, int N) {
    __shared__ float Ws[IN_CH * OUT_CH];   // 32 KB
    int t = threadIdx.x;
    for (int i = t * 4; i < IN_CH * OUT_CH; i += 256 * 4)
        *(float4*)&Ws[i] = *(const float4*)&W[i];
    int cg = t & 15, g = t >> 4;
    float4 att_d = *(const float4*)&att[cg * 4];        // dst half: att[0:64]
    float4 att_s = *(const float4*)&att[64 + cg * 4];   // src half: att[64:128]
    __syncthreads();

    int n0 = blockIdx.x * 64 + g * 4;
    // clamp node indices for loads; guard stores
    int nn[4];
#pragma unroll
    for (int m = 0; m < 4; m++) nn[m] = min(n0 + m, N - 1);

    float4 acc[4];
#pragma unroll
    for (int m = 0; m < 4; m++) acc[m] = make_float4(0.f, 0.f, 0.f, 0.f);

#pragma unroll 2
    for (int k4 = 0; k4 < IN_CH / 4; k4++) {
        float4 xv[4];
#pragma unroll
        for (int m = 0; m < 4; m++)
            xv[m] = *(const float4*)&x[(size_t)nn[m] * IN_CH + k4 * 4];
        float4 wv[4];
#pragma unroll
        for (int j = 0; j < 4; j++)
            wv[j] = *(const float4*)&Ws[(k4 * 4 + j) * OUT_CH + cg * 4];
#pragma unroll
        for (int m = 0; m < 4; m++) {
            acc[m].x = fmaf(xv[m].x, wv[0].x, acc[m].x);
            acc[m].y = fmaf(xv[m].x, wv[0].y, acc[m].y);
            acc[m].z = fmaf(xv[m].x, wv[0].z, acc[m].z);
            acc[m].w = fmaf(xv[m].x, wv[0].w, acc[m].w);
            acc[m].x = fmaf(xv[m].y, wv[1].x, acc[m].x);
            acc[m].y = fmaf(xv[m].y, wv[1].y, acc[m].y);
            acc[m].z = fmaf(xv[m].y, wv[1].z, acc[m].z);
            acc[m].w = fmaf(xv[m].y, wv[1].w, acc[m].w);
            acc[m].x = fmaf(xv[m].z, wv[2].x, acc[m].x);
            acc[m].y = fmaf(xv[m].z, wv[2].y, acc[m].y);
            acc[m].z = fmaf(xv[m].z, wv[2].z, acc[m].z);
            acc[m].w = fmaf(xv[m].z, wv[2].w, acc[m].w);
            acc[m].x = fmaf(xv[m].w, wv[3].x, acc[m].x);
            acc[m].y = fmaf(xv[m].w, wv[3].y, acc[m].y);
            acc[m].z = fmaf(xv[m].w, wv[3].z, acc[m].z);
            acc[m].w = fmaf(xv[m].w, wv[3].w, acc[m].w);
        }
    }

#pragma unroll
    for (int m = 0; m < 4; m++) {
        int node = n0 + m;
        if (node < N)
            *(float4*)&h[(size_t)node * OUT_CH + cg * 4] = acc[m];
        // attention dots: reduce partial over 16 cg lanes (contiguous lanes)
        float pd = acc[m].x * att_d.x + acc[m].y * att_d.y +
                   acc[m].z * att_d.z + acc[m].w * att_d.w;
        float ps = acc[m].x * att_s.x + acc[m].y * att_s.y +
                   acc[m].z * att_s.z + acc[m].w * att_s.w;
#pragma unroll
        for (int msk = 1; msk < 16; msk <<= 1) {
            pd += __shfl_xor(pd, msk, 64);
            ps += __shfl_xor(ps, msk, 64);
        }
        if (cg == 0 && node < N) { adst[node] = pd; asrc[node] = ps; }
    }
}

// ---------- K3a: per-block sums of counts (1024 elems/block) ----------
__global__ __launch_bounds__(256) void k_scanA(const int* __restrict__ counts,
                                               int* __restrict__ partials, int N) {
    __shared__ int red[256];
    int t = threadIdx.x;
    int base = blockIdx.x * 1024 + t * 4;
    int s = 0;
    if (base + 3 < N) {
        int4 v = *(const int4*)(counts + base);
        s = v.x + v.y + v.z + v.w;
    } else {
        for (int i = 0; i < 4; i++) if (base + i < N) s += counts[base + i];
    }
    red[t] = s;
    __syncthreads();
    for (int off = 128; off > 0; off >>= 1) {
        if (t < off) red[t] += red[t + off];
        __syncthreads();
    }
    if (t == 0) partials[blockIdx.x] = red[0];
}

// ---------- K3b: scan the block partials (nb <= 256) + write rowptr[N] ----------
__global__ __launch_bounds__(256) void k_scanB(int* __restrict__ partials, int nb,
                                               int total, int* __restrict__ rowptrN) {
    __shared__ int sh[256];
    int t = threadIdx.x;
    sh[t] = (t < nb) ? partials[t] : 0;
    __syncthreads();
    for (int off = 1; off < 256; off <<= 1) {
        int v = (t >= off) ? sh[t - off] : 0;
        __syncthreads();
        sh[t] += v;
        __syncthreads();
    }
    if (t < nb) partials[t] = (t == 0) ? 0 : sh[t - 1];   // exclusive base
    if (t == 0) *rowptrN = total;
}

// ---------- K3c: re-scan chunk + base -> rowptr, cursor ----------
__global__ __launch_bounds__(256) void k_scanC(const int* __restrict__ counts,
                                               const int* __restrict__ partials,
                                               int* __restrict__ rowptr,
                                               int* __restrict__ cursor, int N) {
    __shared__ int sh[256];
    int t = threadIdx.x;
    int base = blockIdx.x * 1024 + t * 4;
    int c[4];
    int s = 0;
#pragma unroll
    for (int i = 0; i < 4; i++) {
        int idx = base + i;
        c[i] = (idx < N) ? counts[idx] : 0;
        s += c[i];
    }
    sh[t] = s;
    __syncthreads();
    for (int off = 1; off < 256; off <<= 1) {
        int v = (t >= off) ? sh[t - off] : 0;
        __syncthreads();
        sh[t] += v;
        __syncthreads();
    }
    int run = ((t == 0) ? 0 : sh[t - 1]) + partials[blockIdx.x];
#pragma unroll
    for (int i = 0; i < 4; i++) {
        int idx = base + i;
        if (idx < N) {
            rowptr[idx] = run;
            cursor[idx] = run;
            run += c[i];
        }
    }
}

// ---------- K4: per-edge alpha (no segment-max: |alpha|<~10) + CSR scatter ----------
__global__ void k_edge(const void* __restrict__ edges,
                       const float* __restrict__ asrc, const float* __restrict__ adst,
                       int* __restrict__ cursor,
                       int* __restrict__ csr_src, float* __restrict__ csr_alpha,
                       int E, int N) {
    int e = blockIdx.x * blockDim.x + threadIdx.x;
    if (e >= E + N) return;
    int s, d;
    if (e < E) {
        if (sniff_is64(edges)) {
            const long long* p = (const long long*)edges;
            s = (int)p[e];
            d = (int)p[(size_t)E + e];
        } else {
            const int* p = (const int*)edges;
            s = p[e];
            d = p[E + e];
        }
    } else {
        s = d = e - E;   // self loop
    }
    float a = adst[d] + asrc[s];
    a = a > 0.f ? a : NEG_SLOPE * a;   // leaky relu
    int pos = atomicAdd(cursor + d, 1);
    csr_src[pos] = s;
    csr_alpha[pos] = __expf(a);        // store exp(alpha) directly
}

// ---------- K5: per-node gather softmax-aggregate + bias + L2 normalize ----------
__global__ __launch_bounds__(256) void k_agg(const float* __restrict__ h,
                                             const float* __restrict__ csr_alpha,
                                             const int* __restrict__ csr_src,
                                             const int* __restrict__ rowptr,
                                             const float* __restrict__ bias,
                                             float* __restrict__ out, int N) {
    int lane = threadIdx.x & 63;
    int node = blockIdx.x * 4 + (threadIdx.x >> 6);
    if (node >= N) return;
    int b0 = rowptr[node], b1 = rowptr[node + 1];
    float acc0 = 0.f, acc1 = 0.f, esum0 = 0.f, esum1 = 0.f;
    int p = b0;
    for (; p + 1 < b1; p += 2) {
        int s0 = csr_src[p], s1 = csr_src[p + 1];
        float w0 = csr_alpha[p], w1 = csr_alpha[p + 1];
        esum0 += w0;
        esum1 += w1;
        acc0 = fmaf(w0, h[(size_t)s0 * OUT_CH + lane], acc0);
        acc1 = fmaf(w1, h[(size_t)s1 * OUT_CH + lane], acc1);
    }
    if (p < b1) {
        int s0 = csr_src[p];
        float w0 = csr_alpha[p];
        esum0 += w0;
        acc0 = fmaf(w0, h[(size_t)s0 * OUT_CH + lane], acc0);
    }
    float acc = acc0 + acc1, esum = esum0 + esum1;
    float val = acc / (esum + 1e-16f) + bias[lane];
    float ss = val * val;
#pragma unroll
    for (int m = 32; m >= 1; m >>= 1) ss += __shfl_xor(ss, m, 64);
    float nrm = fmaxf(sqrtf(ss), 1e-12f);
    out[(size_t)node * OUT_CH + lane] = val / nrm;
}

extern "C" void kernel_launch(void* const* d_in, const int* in_sizes, int n_in,
                              void* d_out, int out_size, void* d_ws, size_t ws_size,
                              hipStream_t stream) {
    const float* x    = (const float*)d_in[0];
    const void*  edges = d_in[1];
    const float* W    = (const float*)d_in[2];
    const float* att  = (const float*)d_in[3];
    const float* bias = (const float*)d_in[4];
    float* out = (float*)d_out;

    const int N = in_sizes[0] / IN_CH;
    const int E = in_sizes[1] / 2;
    const int EN = E + N;
    const int NB = (N + 1023) / 1024;   // scan blocks (<=256 supported)

    char* ws = (char*)d_ws;
    size_t off = 0;
    auto alloc = [&](size_t bytes) -> void* {
        void* p = ws + off;
        off += bytes;
        off = (off + 255) & ~(size_t)255;
        return p;
    };
    int*   counts    = (int*)alloc((size_t)N * 4);
    int*   rowptr    = (int*)alloc((size_t)(N + 1) * 4);
    int*   cursor    = (int*)alloc((size_t)N * 4);
    int*   partials  = (int*)alloc((size_t)256 * 4);
    float* h         = (float*)alloc((size_t)N * OUT_CH * 4);
    float* asrc      = (float*)alloc((size_t)N * 4);
    float* adst      = (float*)alloc((size_t)N * 4);
    int*   csr_src   = (int*)alloc((size_t)EN * 4);
    float* csr_alpha = (float*)alloc((size_t)EN * 4);

    k_init<<<(N + 255) / 256, 256, 0, stream>>>(counts, N);
    k_count<<<(E + 255) / 256, 256, 0, stream>>>(edges, counts, E);
    k_mm<<<(N + 63) / 64, 256, 0, stream>>>(x, W, att, h, asrc, adst, N);
    k_scanA<<<NB, 256, 0, stream>>>(counts, partials, N);
    k_scanB<<<1, 256, 0, stream>>>(partials, NB, EN, rowptr + N);
    k_scanC<<<NB, 256, 0, stream>>>(counts, partials, rowptr, cursor, N);
    k_edge<<<(EN + 255) / 256, 256, 0, stream>>>(edges, asrc, adst, cursor,
                                                 csr_src, csr_alpha, E, N);
    k_agg<<<(N + 3) / 4, 256, 0, stream>>>(h, csr_alpha, csr_src, rowptr,
                                           bias, out, N);
}

// Round 3
// 221.056 us; speedup vs baseline: 1.9420x; 1.1460x over previous
//
#include <hip/hip_runtime.h>
#include <math.h>

#define IN_CH 128
#define OUT_CH 64
#define NEG_SLOPE 0.2f

// ---------- edge dtype sniff: int64 little-endian => odd int32 words are 0 ----------
__device__ __forceinline__ bool sniff_is64(const void* edges) {
    const unsigned* up = (const unsigned*)edges;
    bool is64 = true;
#pragma unroll
    for (int k = 0; k < 16; k++) is64 = is64 && (up[2 * k + 1] == 0u);
    return is64;
}

// ---------- K0: zero degree counts (self loops handled analytically in k_agg) ----------
__global__ void k_init(int* counts, int N) {
    int i = blockIdx.x * blockDim.x + threadIdx.x;
    if (i < N) counts[i] = 0;
}

// ---------- K1: degree count + per-edge rank (sequential write) ----------
__global__ void k_count(const void* __restrict__ edges, int* __restrict__ counts,
                        int* __restrict__ rank, int E) {
    int e = blockIdx.x * blockDim.x + threadIdx.x;
    if (e >= E) return;
    int d;
    if (sniff_is64(edges)) d = (int)((const long long*)edges)[(size_t)E + e];
    else                   d = ((const int*)edges)[E + e];
    rank[e] = atomicAdd(counts + d, 1);
}

// ---------- K2: h = x @ W + per-node attention dots ----------
__global__ __launch_bounds__(256) void k_mm(const float* __restrict__ x,
                                            const float* __restrict__ W,
                                            const float* __restrict__ att,
                                            float* __restrict__ h,
                                            float* __restrict__ asrc,
                                            float* __restrict__ adst, int N) {
    __shared__ float Ws[IN_CH * OUT_CH];   // 32 KB
    int t = threadIdx.x;
    for (int i = t * 4; i < IN_CH * OUT_CH; i += 256 * 4)
        *(float4*)&Ws[i] = *(const float4*)&W[i];
    int cg = t & 15, g = t >> 4;
    float4 att_d = *(const float4*)&att[cg * 4];        // dst half: att[0:64]
    float4 att_s = *(const float4*)&att[64 + cg * 4];   // src half: att[64:128]
    __syncthreads();

    int n0 = blockIdx.x * 64 + g * 4;
    int nn[4];
#pragma unroll
    for (int m = 0; m < 4; m++) nn[m] = min(n0 + m, N - 1);

    float4 acc[4];
#pragma unroll
    for (int m = 0; m < 4; m++) acc[m] = make_float4(0.f, 0.f, 0.f, 0.f);

#pragma unroll 2
    for (int k4 = 0; k4 < IN_CH / 4; k4++) {
        float4 xv[4];
#pragma unroll
        for (int m = 0; m < 4; m++)
            xv[m] = *(const float4*)&x[(size_t)nn[m] * IN_CH + k4 * 4];
        float4 wv[4];
#pragma unroll
        for (int j = 0; j < 4; j++)
            wv[j] = *(const float4*)&Ws[(k4 * 4 + j) * OUT_CH + cg * 4];
#pragma unroll
        for (int m = 0; m < 4; m++) {
            acc[m].x = fmaf(xv[m].x, wv[0].x, acc[m].x);
            acc[m].y = fmaf(xv[m].x, wv[0].y, acc[m].y);
            acc[m].z = fmaf(xv[m].x, wv[0].z, acc[m].z);
            acc[m].w = fmaf(xv[m].x, wv[0].w, acc[m].w);
            acc[m].x = fmaf(xv[m].y, wv[1].x, acc[m].x);
            acc[m].y = fmaf(xv[m].y, wv[1].y, acc[m].y);
            acc[m].z = fmaf(xv[m].y, wv[1].z, acc[m].z);
            acc[m].w = fmaf(xv[m].y, wv[1].w, acc[m].w);
            acc[m].x = fmaf(xv[m].z, wv[2].x, acc[m].x);
            acc[m].y = fmaf(xv[m].z, wv[2].y, acc[m].y);
            acc[m].z = fmaf(xv[m].z, wv[2].z, acc[m].z);
            acc[m].w = fmaf(xv[m].z, wv[2].w, acc[m].w);
            acc[m].x = fmaf(xv[m].w, wv[3].x, acc[m].x);
            acc[m].y = fmaf(xv[m].w, wv[3].y, acc[m].y);
            acc[m].z = fmaf(xv[m].w, wv[3].z, acc[m].z);
            acc[m].w = fmaf(xv[m].w, wv[3].w, acc[m].w);
        }
    }

#pragma unroll
    for (int m = 0; m < 4; m++) {
        int node = n0 + m;
        if (node < N)
            *(float4*)&h[(size_t)node * OUT_CH + cg * 4] = acc[m];
        float pd = acc[m].x * att_d.x + acc[m].y * att_d.y +
                   acc[m].z * att_d.z + acc[m].w * att_d.w;
        float ps = acc[m].x * att_s.x + acc[m].y * att_s.y +
                   acc[m].z * att_s.z + acc[m].w * att_s.w;
#pragma unroll
        for (int msk = 1; msk < 16; msk <<= 1) {
            pd += __shfl_xor(pd, msk, 64);
            ps += __shfl_xor(ps, msk, 64);
        }
        if (cg == 0 && node < N) { adst[node] = pd; asrc[node] = ps; }
    }
}

// ---------- K3a: per-block sums of counts (1024 elems/block) ----------
__global__ __launch_bounds__(256) void k_scanA(const int* __restrict__ counts,
                                               int* __restrict__ partials, int N) {
    __shared__ int red[256];
    int t = threadIdx.x;
    int base = blockIdx.x * 1024 + t * 4;
    int s = 0;
    if (base + 3 < N) {
        int4 v = *(const int4*)(counts + base);
        s = v.x + v.y + v.z + v.w;
    } else {
        for (int i = 0; i < 4; i++) if (base + i < N) s += counts[base + i];
    }
    red[t] = s;
    __syncthreads();
    for (int off = 128; off > 0; off >>= 1) {
        if (t < off) red[t] += red[t + off];
        __syncthreads();
    }
    if (t == 0) partials[blockIdx.x] = red[0];
}

// ---------- K3b: scan the block partials (nb <= 256) + write rowptr[N] ----------
__global__ __launch_bounds__(256) void k_scanB(int* __restrict__ partials, int nb,
                                               int total, int* __restrict__ rowptrN) {
    __shared__ int sh[256];
    int t = threadIdx.x;
    sh[t] = (t < nb) ? partials[t] : 0;
    __syncthreads();
    for (int off = 1; off < 256; off <<= 1) {
        int v = (t >= off) ? sh[t - off] : 0;
        __syncthreads();
        sh[t] += v;
        __syncthreads();
    }
    if (t < nb) partials[t] = (t == 0) ? 0 : sh[t - 1];   // exclusive base
    if (t == 0) *rowptrN = total;
}

// ---------- K3c: re-scan chunk + base -> rowptr ----------
__global__ __launch_bounds__(256) void k_scanC(const int* __restrict__ counts,
                                               const int* __restrict__ partials,
                                               int* __restrict__ rowptr, int N) {
    __shared__ int sh[256];
    int t = threadIdx.x;
    int base = blockIdx.x * 1024 + t * 4;
    int c[4];
    int s = 0;
#pragma unroll
    for (int i = 0; i < 4; i++) {
        int idx = base + i;
        c[i] = (idx < N) ? counts[idx] : 0;
        s += c[i];
    }
    sh[t] = s;
    __syncthreads();
    for (int off = 1; off < 256; off <<= 1) {
        int v = (t >= off) ? sh[t - off] : 0;
        __syncthreads();
        sh[t] += v;
        __syncthreads();
    }
    int run = ((t == 0) ? 0 : sh[t - 1]) + partials[blockIdx.x];
#pragma unroll
    for (int i = 0; i < 4; i++) {
        int idx = base + i;
        if (idx < N) {
            rowptr[idx] = run;
            run += c[i];
        }
    }
}

// ---------- K4: CSR scatter, no atomics, 4 B payload ----------
__global__ void k_scatter(const void* __restrict__ edges,
                          const int* __restrict__ rank,
                          const int* __restrict__ rowptr,
                          int* __restrict__ csr_src, int E) {
    int e = blockIdx.x * blockDim.x + threadIdx.x;
    if (e >= E) return;
    int s, d;
    if (sniff_is64(edges)) {
        const long long* p = (const long long*)edges;
        s = (int)p[e];
        d = (int)p[(size_t)E + e];
    } else {
        const int* p = (const int*)edges;
        s = p[e];
        d = p[E + e];
    }
    csr_src[rowptr[d] + rank[e]] = s;
}

// ---------- K5: per-node gather softmax-aggregate + bias + L2 normalize ----------
__global__ __launch_bounds__(256) void k_agg(const float* __restrict__ h,
                                             const int* __restrict__ csr_src,
                                             const int* __restrict__ rowptr,
                                             const float* __restrict__ asrc,
                                             const float* __restrict__ adst,
                                             const float* __restrict__ bias,
                                             float* __restrict__ out, int N) {
    int lane = threadIdx.x & 63;
    int node = blockIdx.x * 4 + (threadIdx.x >> 6);
    if (node >= N) return;
    float aD = adst[node];
    // self loop handled analytically
    float a = aD + asrc[node];
    a = a > 0.f ? a : NEG_SLOPE * a;
    float w = __expf(a);
    float esum0 = w, esum1 = 0.f;
    float acc0 = w * h[(size_t)node * OUT_CH + lane], acc1 = 0.f;

    int b0 = rowptr[node], b1 = rowptr[node + 1];
    int p = b0;
    for (; p + 1 < b1; p += 2) {
        int s0 = csr_src[p], s1 = csr_src[p + 1];
        float a0 = aD + asrc[s0];
        float a1 = aD + asrc[s1];
        a0 = a0 > 0.f ? a0 : NEG_SLOPE * a0;
        a1 = a1 > 0.f ? a1 : NEG_SLOPE * a1;
        float w0 = __expf(a0), w1 = __expf(a1);
        esum0 += w0;
        esum1 += w1;
        acc0 = fmaf(w0, h[(size_t)s0 * OUT_CH + lane], acc0);
        acc1 = fmaf(w1, h[(size_t)s1 * OUT_CH + lane], acc1);
    }
    if (p < b1) {
        int s0 = csr_src[p];
        float a0 = aD + asrc[s0];
        a0 = a0 > 0.f ? a0 : NEG_SLOPE * a0;
        float w0 = __expf(a0);
        esum0 += w0;
        acc0 = fmaf(w0, h[(size_t)s0 * OUT_CH + lane], acc0);
    }
    float acc = acc0 + acc1, esum = esum0 + esum1;
    float val = acc / (esum + 1e-16f) + bias[lane];
    float ss = val * val;
#pragma unroll
    for (int m = 32; m >= 1; m >>= 1) ss += __shfl_xor(ss, m, 64);
    float nrm = fmaxf(sqrtf(ss), 1e-12f);
    out[(size_t)node * OUT_CH + lane] = val / nrm;
}

extern "C" void kernel_launch(void* const* d_in, const int* in_sizes, int n_in,
                              void* d_out, int out_size, void* d_ws, size_t ws_size,
                              hipStream_t stream) {
    const float* x    = (const float*)d_in[0];
    const void*  edges = d_in[1];
    const float* W    = (const float*)d_in[2];
    const float* att  = (const float*)d_in[3];
    const float* bias = (const float*)d_in[4];
    float* out = (float*)d_out;

    const int N = in_sizes[0] / IN_CH;
    const int E = in_sizes[1] / 2;
    const int NB = (N + 1023) / 1024;   // scan blocks (<=256 supported)

    char* ws = (char*)d_ws;
    size_t off = 0;
    auto alloc = [&](size_t bytes) -> void* {
        void* p = ws + off;
        off += bytes;
        off = (off + 255) & ~(size_t)255;
        return p;
    };
    int*   counts   = (int*)alloc((size_t)N * 4);
    int*   rowptr   = (int*)alloc((size_t)(N + 1) * 4);
    int*   rank     = (int*)alloc((size_t)E * 4);
    int*   partials = (int*)alloc((size_t)256 * 4);
    float* h        = (float*)alloc((size_t)N * OUT_CH * 4);
    float* asrc     = (float*)alloc((size_t)N * 4);
    float* adst     = (float*)alloc((size_t)N * 4);
    int*   csr_src  = (int*)alloc((size_t)E * 4);

    k_init<<<(N + 255) / 256, 256, 0, stream>>>(counts, N);
    k_count<<<(E + 255) / 256, 256, 0, stream>>>(edges, counts, rank, E);
    k_mm<<<(N + 63) / 64, 256, 0, stream>>>(x, W, att, h, asrc, adst, N);
    k_scanA<<<NB, 256, 0, stream>>>(counts, partials, N);
    k_scanB<<<1, 256, 0, stream>>>(partials, NB, E, rowptr + N);
    k_scanC<<<NB, 256, 0, stream>>>(counts, partials, rowptr, N);
    k_scatter<<<(E + 255) / 256, 256, 0, stream>>>(edges, rank, rowptr, csr_src, E);
    k_agg<<<(N + 3) / 4, 256, 0, stream>>>(h, csr_src, rowptr, asrc, adst,
                                           bias, out, N);
}

// Round 4
// 189.266 us; speedup vs baseline: 2.2682x; 1.1680x over previous
//
#include <hip/hip_runtime.h>
#include <math.h>

#define IN_CH 128
#define OUT_CH 64
#define NEG_SLOPE 0.2f

// ---------- bf16 helpers ----------
__device__ __forceinline__ unsigned short f2bf(float f) {
    unsigned u = __float_as_uint(f);
    unsigned r = (u + 0x7FFFu + ((u >> 16) & 1u)) >> 16;   // round-nearest-even
    return (unsigned short)r;
}
__device__ __forceinline__ float bf2f(unsigned short b) {
    return __uint_as_float((unsigned)b << 16);
}

// ---------- edge dtype sniff: int64 little-endian => odd int32 words are 0 ----------
__device__ __forceinline__ bool sniff_is64(const void* edges) {
    const unsigned* up = (const unsigned*)edges;
    bool is64 = true;
#pragma unroll
    for (int k = 0; k < 16; k++) is64 = is64 && (up[2 * k + 1] == 0u);
    return is64;
}

// ---------- K0: zero degree counts (self loops handled analytically in k_agg) ----------
__global__ void k_init(int* counts, int N) {
    int i = blockIdx.x * blockDim.x + threadIdx.x;
    if (i < N) counts[i] = 0;
}

// ---------- K1: degree count + per-edge rank (sequential write) ----------
__global__ void k_count(const void* __restrict__ edges, int* __restrict__ counts,
                        int* __restrict__ rank, int E) {
    int e = blockIdx.x * blockDim.x + threadIdx.x;
    if (e >= E) return;
    int d;
    if (sniff_is64(edges)) d = (int)((const long long*)edges)[(size_t)E + e];
    else                   d = ((const int*)edges)[E + e];
    rank[e] = atomicAdd(counts + d, 1);
}

// ---------- K2: h16 = bf16(x @ W) + per-node attention dots ----------
__global__ __launch_bounds__(256) void k_mm(const float* __restrict__ x,
                                            const float* __restrict__ W,
                                            const float* __restrict__ att,
                                            unsigned short* __restrict__ h16,
                                            float* __restrict__ asrc,
                                            float* __restrict__ adst, int N) {
    __shared__ float Ws[IN_CH * OUT_CH];   // 32 KB
    int t = threadIdx.x;
    for (int i = t * 4; i < IN_CH * OUT_CH; i += 256 * 4)
        *(float4*)&Ws[i] = *(const float4*)&W[i];
    int cg = t & 15, g = t >> 4;
    float4 att_d = *(const float4*)&att[cg * 4];        // dst half: att[0:64]
    float4 att_s = *(const float4*)&att[64 + cg * 4];   // src half: att[64:128]
    __syncthreads();

    int n0 = blockIdx.x * 64 + g * 4;
    int nn[4];
#pragma unroll
    for (int m = 0; m < 4; m++) nn[m] = min(n0 + m, N - 1);

    float4 acc[4];
#pragma unroll
    for (int m = 0; m < 4; m++) acc[m] = make_float4(0.f, 0.f, 0.f, 0.f);

#pragma unroll 2
    for (int k4 = 0; k4 < IN_CH / 4; k4++) {
        float4 xv[4];
#pragma unroll
        for (int m = 0; m < 4; m++)
            xv[m] = *(const float4*)&x[(size_t)nn[m] * IN_CH + k4 * 4];
        float4 wv[4];
#pragma unroll
        for (int j = 0; j < 4; j++)
            wv[j] = *(const float4*)&Ws[(k4 * 4 + j) * OUT_CH + cg * 4];
#pragma unroll
        for (int m = 0; m < 4; m++) {
            acc[m].x = fmaf(xv[m].x, wv[0].x, acc[m].x);
            acc[m].y = fmaf(xv[m].x, wv[0].y, acc[m].y);
            acc[m].z = fmaf(xv[m].x, wv[0].z, acc[m].z);
            acc[m].w = fmaf(xv[m].x, wv[0].w, acc[m].w);
            acc[m].x = fmaf(xv[m].y, wv[1].x, acc[m].x);
            acc[m].y = fmaf(xv[m].y, wv[1].y, acc[m].y);
            acc[m].z = fmaf(xv[m].y, wv[1].z, acc[m].z);
            acc[m].w = fmaf(xv[m].y, wv[1].w, acc[m].w);
            acc[m].x = fmaf(xv[m].z, wv[2].x, acc[m].x);
            acc[m].y = fmaf(xv[m].z, wv[2].y, acc[m].y);
            acc[m].z = fmaf(xv[m].z, wv[2].z, acc[m].z);
            acc[m].w = fmaf(xv[m].z, wv[2].w, acc[m].w);
            acc[m].x = fmaf(xv[m].w, wv[3].x, acc[m].x);
            acc[m].y = fmaf(xv[m].w, wv[3].y, acc[m].y);
            acc[m].z = fmaf(xv[m].w, wv[3].z, acc[m].z);
            acc[m].w = fmaf(xv[m].w, wv[3].w, acc[m].w);
        }
    }

#pragma unroll
    for (int m = 0; m < 4; m++) {
        int node = n0 + m;
        if (node < N) {
            ushort4 hv;
            hv.x = f2bf(acc[m].x);
            hv.y = f2bf(acc[m].y);
            hv.z = f2bf(acc[m].z);
            hv.w = f2bf(acc[m].w);
            *(ushort4*)&h16[(size_t)node * OUT_CH + cg * 4] = hv;
        }
        float pd = acc[m].x * att_d.x + acc[m].y * att_d.y +
                   acc[m].z * att_d.z + acc[m].w * att_d.w;
        float ps = acc[m].x * att_s.x + acc[m].y * att_s.y +
                   acc[m].z * att_s.z + acc[m].w * att_s.w;
#pragma unroll
        for (int msk = 1; msk < 16; msk <<= 1) {
            pd += __shfl_xor(pd, msk, 64);
            ps += __shfl_xor(ps, msk, 64);
        }
        if (cg == 0 && node < N) { adst[node] = pd; asrc[node] = ps; }
    }
}

// ---------- K3a: per-block sums of counts (1024 elems/block) ----------
__global__ __launch_bounds__(256) void k_scanA(const int* __restrict__ counts,
                                               int* __restrict__ partials, int N) {
    __shared__ int red[256];
    int t = threadIdx.x;
    int base = blockIdx.x * 1024 + t * 4;
    int s = 0;
    if (base + 3 < N) {
        int4 v = *(const int4*)(counts + base);
        s = v.x + v.y + v.z + v.w;
    } else {
        for (int i = 0; i < 4; i++) if (base + i < N) s += counts[base + i];
    }
    red[t] = s;
    __syncthreads();
    for (int off = 128; off > 0; off >>= 1) {
        if (t < off) red[t] += red[t + off];
        __syncthreads();
    }
    if (t == 0) partials[blockIdx.x] = red[0];
}

// ---------- K3b: scan the block partials (nb <= 256) + write rowptr[N] ----------
__global__ __launch_bounds__(256) void k_scanB(int* __restrict__ partials, int nb,
                                               int total, int* __restrict__ rowptrN) {
    __shared__ int sh[256];
    int t = threadIdx.x;
    sh[t] = (t < nb) ? partials[t] : 0;
    __syncthreads();
    for (int off = 1; off < 256; off <<= 1) {
        int v = (t >= off) ? sh[t - off] : 0;
        __syncthreads();
        sh[t] += v;
        __syncthreads();
    }
    if (t < nb) partials[t] = (t == 0) ? 0 : sh[t - 1];   // exclusive base
    if (t == 0) *rowptrN = total;
}

// ---------- K3c: re-scan chunk + base -> rowptr ----------
__global__ __launch_bounds__(256) void k_scanC(const int* __restrict__ counts,
                                               const int* __restrict__ partials,
                                               int* __restrict__ rowptr, int N) {
    __shared__ int sh[256];
    int t = threadIdx.x;
    int base = blockIdx.x * 1024 + t * 4;
    int c[4];
    int s = 0;
#pragma unroll
    for (int i = 0; i < 4; i++) {
        int idx = base + i;
        c[i] = (idx < N) ? counts[idx] : 0;
        s += c[i];
    }
    sh[t] = s;
    __syncthreads();
    for (int off = 1; off < 256; off <<= 1) {
        int v = (t >= off) ? sh[t - off] : 0;
        __syncthreads();
        sh[t] += v;
        __syncthreads();
    }
    int run = ((t == 0) ? 0 : sh[t - 1]) + partials[blockIdx.x];
#pragma unroll
    for (int i = 0; i < 4; i++) {
        int idx = base + i;
        if (idx < N) {
            rowptr[idx] = run;
            run += c[i];
        }
    }
}

// ---------- K4: CSR scatter, no atomics, 4 B payload ----------
__global__ void k_scatter(const void* __restrict__ edges,
                          const int* __restrict__ rank,
                          const int* __restrict__ rowptr,
                          int* __restrict__ csr_src, int E) {
    int e = blockIdx.x * blockDim.x + threadIdx.x;
    if (e >= E) return;
    int s, d;
    if (sniff_is64(edges)) {
        const long long* p = (const long long*)edges;
        s = (int)p[e];
        d = (int)p[(size_t)E + e];
    } else {
        const int* p = (const int*)edges;
        s = p[e];
        d = p[E + e];
    }
    csr_src[rowptr[d] + rank[e]] = s;
}

// ---------- K5: per-node gather softmax-aggregate + bias + L2 normalize ----------
// 1 wave per node. Per 64-edge chunk: lanes cooperatively compute (src, exp-weight)
// once per edge (coalesced csr read, parallel asrc gather), stage pairs in
// wave-private LDS, wave-reduce esum, then gather bf16 h rows 4-deep.
__global__ __launch_bounds__(256) void k_agg(const unsigned short* __restrict__ h16,
                                             const int* __restrict__ csr_src,
                                             const int* __restrict__ rowptr,
                                             const float* __restrict__ asrc,
                                             const float* __restrict__ adst,
                                             const float* __restrict__ bias,
                                             float* __restrict__ out, int N) {
    __shared__ float2 stage[4][64];   // wave-private, no barriers needed
    int lane = threadIdx.x & 63;
    int wid = threadIdx.x >> 6;
    int node = blockIdx.x * 4 + wid;
    if (node >= N) return;

    float aD = adst[node];
    // analytic self loop
    float a = aD + asrc[node];
    a = a > 0.f ? a : NEG_SLOPE * a;
    float w_self = __expf(a);
    float esum = w_self;
    float acc0 = w_self * bf2f(h16[(size_t)node * OUT_CH + lane]);
    float acc1 = 0.f;

    int b0 = rowptr[node], b1 = rowptr[node + 1];
    for (int base = b0; base < b1; base += 64) {
        int idx = base + lane;
        int sv = 0;
        float wv = 0.f;
        if (idx < b1) {
            sv = csr_src[idx];                     // coalesced
            float av = aD + asrc[sv];              // 64-wide parallel gather (L2-hot)
            av = av > 0.f ? av : NEG_SLOPE * av;
            wv = __expf(av);                       // once per edge, not per lane
        }
        float ws = wv;
#pragma unroll
        for (int m = 32; m >= 1; m >>= 1) ws += __shfl_xor(ws, m, 64);
        esum += ws;
        stage[wid][lane] = make_float2(__int_as_float(sv), wv);

        int n = min(64, b1 - base);
        int j = 0;
        for (; j + 4 <= n; j += 4) {
            float2 p0 = stage[wid][j + 0];
            float2 p1 = stage[wid][j + 1];
            float2 p2 = stage[wid][j + 2];
            float2 p3 = stage[wid][j + 3];
            float r0 = bf2f(h16[((size_t)__float_as_int(p0.x) << 6) + lane]);
            float r1 = bf2f(h16[((size_t)__float_as_int(p1.x) << 6) + lane]);
            float r2 = bf2f(h16[((size_t)__float_as_int(p2.x) << 6) + lane]);
            float r3 = bf2f(h16[((size_t)__float_as_int(p3.x) << 6) + lane]);
            acc0 = fmaf(p0.y, r0, acc0);
            acc1 = fmaf(p1.y, r1, acc1);
            acc0 = fmaf(p2.y, r2, acc0);
            acc1 = fmaf(p3.y, r3, acc1);
        }
        for (; j < n; j++) {
            float2 p0 = stage[wid][j];
            float r0 = bf2f(h16[((size_t)__float_as_int(p0.x) << 6) + lane]);
            acc0 = fmaf(p0.y, r0, acc0);
        }
    }
    float acc = acc0 + acc1;
    float val = acc / (esum + 1e-16f) + bias[lane];
    float ss = val * val;
#pragma unroll
    for (int m = 32; m >= 1; m >>= 1) ss += __shfl_xor(ss, m, 64);
    float nrm = fmaxf(sqrtf(ss), 1e-12f);
    out[(size_t)node * OUT_CH + lane] = val / nrm;
}

extern "C" void kernel_launch(void* const* d_in, const int* in_sizes, int n_in,
                              void* d_out, int out_size, void* d_ws, size_t ws_size,
                              hipStream_t stream) {
    const float* x    = (const float*)d_in[0];
    const void*  edges = d_in[1];
    const float* W    = (const float*)d_in[2];
    const float* att  = (const float*)d_in[3];
    const float* bias = (const float*)d_in[4];
    float* out = (float*)d_out;

    const int N = in_sizes[0] / IN_CH;
    const int E = in_sizes[1] / 2;
    const int NB = (N + 1023) / 1024;   // scan blocks (<=256 supported)

    char* ws = (char*)d_ws;
    size_t off = 0;
    auto alloc = [&](size_t bytes) -> void* {
        void* p = ws + off;
        off += bytes;
        off = (off + 255) & ~(size_t)255;
        return p;
    };
    int*            counts   = (int*)alloc((size_t)N * 4);
    int*            rowptr   = (int*)alloc((size_t)(N + 1) * 4);
    int*            rank     = (int*)alloc((size_t)E * 4);
    int*            partials = (int*)alloc((size_t)256 * 4);
    unsigned short* h16      = (unsigned short*)alloc((size_t)N * OUT_CH * 2);
    float*          asrc     = (float*)alloc((size_t)N * 4);
    float*          adst     = (float*)alloc((size_t)N * 4);
    int*            csr_src  = (int*)alloc((size_t)E * 4);

    k_init<<<(N + 255) / 256, 256, 0, stream>>>(counts, N);
    k_count<<<(E + 255) / 256, 256, 0, stream>>>(edges, counts, rank, E);
    k_mm<<<(N + 63) / 64, 256, 0, stream>>>(x, W, att, h16, asrc, adst, N);
    k_scanA<<<NB, 256, 0, stream>>>(counts, partials, N);
    k_scanB<<<1, 256, 0, stream>>>(partials, NB, E, rowptr + N);
    k_scanC<<<NB, 256, 0, stream>>>(counts, partials, rowptr, N);
    k_scatter<<<(E + 255) / 256, 256, 0, stream>>>(edges, rank, rowptr, csr_src, E);
    k_agg<<<(N + 3) / 4, 256, 0, stream>>>(h16, csr_src, rowptr, asrc, adst,
                                           bias, out, N);
}

// Round 5
// 165.708 us; speedup vs baseline: 2.5907x; 1.1422x over previous
//
#include <hip/hip_runtime.h>
#include <math.h>

#define IN_CH 128
#define OUT_CH 64
#define NEG_SLOPE 0.2f

// ---------- bf16 helpers ----------
__device__ __forceinline__ unsigned short f2bf(float f) {
    unsigned u = __float_as_uint(f);
    unsigned r = (u + 0x7FFFu + ((u >> 16) & 1u)) >> 16;   // round-nearest-even
    return (unsigned short)r;
}

// ---------- edge dtype sniff: int64 little-endian => odd int32 words are 0 ----------
__device__ __forceinline__ bool sniff_is64(const void* edges) {
    const unsigned* up = (const unsigned*)edges;
    bool is64 = true;
#pragma unroll
    for (int k = 0; k < 16; k++) is64 = is64 && (up[2 * k + 1] == 0u);
    return is64;
}

// ---------- K0: zero degree counts (self loops handled analytically in k_agg) ----------
__global__ void k_init(int* counts, int N) {
    int i = blockIdx.x * blockDim.x + threadIdx.x;
    if (i < N) counts[i] = 0;
}

// ---------- K1 (fused): blocks [0,mmb) do h16 = bf16(x@W) + att dots;
//                        blocks [mmb,..) do degree count + rank (2 edges/thread) ----------
__global__ __launch_bounds__(256) void k_mm_count(
        const float* __restrict__ x, const float* __restrict__ W,
        const float* __restrict__ att, unsigned short* __restrict__ h16,
        float* __restrict__ asrc, float* __restrict__ adst, int N,
        const void* __restrict__ edges, int* __restrict__ counts,
        unsigned short* __restrict__ rank, int E, int mmb) {
    __shared__ float Ws[IN_CH * OUT_CH];   // 32 KB (mm path only)
    int t = threadIdx.x;
    if ((int)blockIdx.x >= mmb) {
        // ----- count path -----
        int e0 = ((blockIdx.x - mmb) * 256 + t) * 2;
        if (e0 >= E) return;
        bool has1 = (e0 + 1 < E);
        int d0, d1 = 0;
        if (sniff_is64(edges)) {
            const long long* p = (const long long*)edges;
            int4 v = *(const int4*)&p[(size_t)E + e0];   // e0,E even -> 16B aligned
            d0 = v.x; d1 = v.z;
        } else {
            const int* p = (const int*)edges;
            int2 v = *(const int2*)&p[E + e0];
            d0 = v.x; d1 = v.y;
        }
        rank[e0] = (unsigned short)atomicAdd(counts + d0, 1);
        if (has1) rank[e0 + 1] = (unsigned short)atomicAdd(counts + d1, 1);
        return;
    }
    // ----- mm path -----
    for (int i = t * 4; i < IN_CH * OUT_CH; i += 256 * 4)
        *(float4*)&Ws[i] = *(const float4*)&W[i];
    int cg = t & 15, g = t >> 4;
    float4 att_d = *(const float4*)&att[cg * 4];        // dst half: att[0:64]
    float4 att_s = *(const float4*)&att[64 + cg * 4];   // src half: att[64:128]
    __syncthreads();

    int n0 = blockIdx.x * 64 + g * 4;
    int nn[4];
#pragma unroll
    for (int m = 0; m < 4; m++) nn[m] = min(n0 + m, N - 1);

    float4 acc[4];
#pragma unroll
    for (int m = 0; m < 4; m++) acc[m] = make_float4(0.f, 0.f, 0.f, 0.f);

#pragma unroll 2
    for (int k4 = 0; k4 < IN_CH / 4; k4++) {
        float4 xv[4];
#pragma unroll
        for (int m = 0; m < 4; m++)
            xv[m] = *(const float4*)&x[(size_t)nn[m] * IN_CH + k4 * 4];
        float4 wv[4];
#pragma unroll
        for (int j = 0; j < 4; j++)
            wv[j] = *(const float4*)&Ws[(k4 * 4 + j) * OUT_CH + cg * 4];
#pragma unroll
        for (int m = 0; m < 4; m++) {
            acc[m].x = fmaf(xv[m].x, wv[0].x, acc[m].x);
            acc[m].y = fmaf(xv[m].x, wv[0].y, acc[m].y);
            acc[m].z = fmaf(xv[m].x, wv[0].z, acc[m].z);
            acc[m].w = fmaf(xv[m].x, wv[0].w, acc[m].w);
            acc[m].x = fmaf(xv[m].y, wv[1].x, acc[m].x);
            acc[m].y = fmaf(xv[m].y, wv[1].y, acc[m].y);
            acc[m].z = fmaf(xv[m].y, wv[1].z, acc[m].z);
            acc[m].w = fmaf(xv[m].y, wv[1].w, acc[m].w);
            acc[m].x = fmaf(xv[m].z, wv[2].x, acc[m].x);
            acc[m].y = fmaf(xv[m].z, wv[2].y, acc[m].y);
            acc[m].z = fmaf(xv[m].z, wv[2].z, acc[m].z);
            acc[m].w = fmaf(xv[m].z, wv[2].w, acc[m].w);
            acc[m].x = fmaf(xv[m].w, wv[3].x, acc[m].x);
            acc[m].y = fmaf(xv[m].w, wv[3].y, acc[m].y);
            acc[m].z = fmaf(xv[m].w, wv[3].z, acc[m].z);
            acc[m].w = fmaf(xv[m].w, wv[3].w, acc[m].w);
        }
    }

#pragma unroll
    for (int m = 0; m < 4; m++) {
        int node = n0 + m;
        if (node < N) {
            ushort4 hv;
            hv.x = f2bf(acc[m].x);
            hv.y = f2bf(acc[m].y);
            hv.z = f2bf(acc[m].z);
            hv.w = f2bf(acc[m].w);
            *(ushort4*)&h16[(size_t)node * OUT_CH + cg * 4] = hv;
        }
        float pd = acc[m].x * att_d.x + acc[m].y * att_d.y +
                   acc[m].z * att_d.z + acc[m].w * att_d.w;
        float ps = acc[m].x * att_s.x + acc[m].y * att_s.y +
                   acc[m].z * att_s.z + acc[m].w * att_s.w;
#pragma unroll
        for (int msk = 1; msk < 16; msk <<= 1) {
            pd += __shfl_xor(pd, msk, 64);
            ps += __shfl_xor(ps, msk, 64);
        }
        if (cg == 0 && node < N) { adst[node] = pd; asrc[node] = ps; }
    }
}

// ---------- K2a: per-block sums of counts (1024 elems/block) ----------
__global__ __launch_bounds__(256) void k_scanA(const int* __restrict__ counts,
                                               int* __restrict__ partials, int N) {
    __shared__ int red[256];
    int t = threadIdx.x;
    int base = blockIdx.x * 1024 + t * 4;
    int s = 0;
    if (base + 3 < N) {
        int4 v = *(const int4*)(counts + base);
        s = v.x + v.y + v.z + v.w;
    } else {
        for (int i = 0; i < 4; i++) if (base + i < N) s += counts[base + i];
    }
    red[t] = s;
    __syncthreads();
    for (int off = 128; off > 0; off >>= 1) {
        if (t < off) red[t] += red[t + off];
        __syncthreads();
    }
    if (t == 0) partials[blockIdx.x] = red[0];
}

// ---------- K2b: each block scans the partials itself, then re-scans its chunk ----------
__global__ __launch_bounds__(256) void k_scanC(const int* __restrict__ counts,
                                               const int* __restrict__ partials,
                                               int nb, int total,
                                               int* __restrict__ rowptr, int N) {
    __shared__ int shp[256];
    __shared__ int sh[256];
    int t = threadIdx.x;
    shp[t] = (t < nb) ? partials[t] : 0;
    __syncthreads();
    for (int off = 1; off < 256; off <<= 1) {
        int v = (t >= off) ? shp[t - off] : 0;
        __syncthreads();
        shp[t] += v;
        __syncthreads();
    }
    int base_blk = (blockIdx.x == 0) ? 0 : shp[blockIdx.x - 1];

    int base = blockIdx.x * 1024 + t * 4;
    int c[4];
    int s = 0;
#pragma unroll
    for (int i = 0; i < 4; i++) {
        int idx = base + i;
        c[i] = (idx < N) ? counts[idx] : 0;
        s += c[i];
    }
    sh[t] = s;
    __syncthreads();
    for (int off = 1; off < 256; off <<= 1) {
        int v = (t >= off) ? sh[t - off] : 0;
        __syncthreads();
        sh[t] += v;
        __syncthreads();
    }
    int run = ((t == 0) ? 0 : sh[t - 1]) + base_blk;
#pragma unroll
    for (int i = 0; i < 4; i++) {
        int idx = base + i;
        if (idx < N) {
            rowptr[idx] = run;
            run += c[i];
        }
    }
    if (blockIdx.x == 0 && t == 0) rowptr[N] = total;
}

// ---------- K3: CSR scatter, no atomics, 4 B payload, 2 edges/thread ----------
__global__ void k_scatter(const void* __restrict__ edges,
                          const unsigned short* __restrict__ rank,
                          const int* __restrict__ rowptr,
                          int* __restrict__ csr_src, int E) {
    int e0 = (blockIdx.x * blockDim.x + threadIdx.x) * 2;
    if (e0 >= E) return;
    bool has1 = (e0 + 1 < E);
    int s0, s1 = 0, d0, d1 = 0;
    if (sniff_is64(edges)) {
        const long long* p = (const long long*)edges;
        int4 vs = *(const int4*)&p[e0];
        int4 vd = *(const int4*)&p[(size_t)E + e0];
        s0 = vs.x; s1 = vs.z;
        d0 = vd.x; d1 = vd.z;
    } else {
        const int* p = (const int*)edges;
        int2 vs = *(const int2*)&p[e0];
        int2 vd = *(const int2*)&p[E + e0];
        s0 = vs.x; s1 = vs.y;
        d0 = vd.x; d1 = vd.y;
    }
    ushort2 r = *(const ushort2*)&rank[e0];
    csr_src[rowptr[d0] + r.x] = s0;
    if (has1) csr_src[rowptr[d1] + r.y] = s1;
}

// ---------- K4: per-node gather softmax-aggregate + bias + L2 normalize ----------
// 1 wave/node, 2 channels/lane (ushort2), half-waves cover 2 src rows per load.
__global__ __launch_bounds__(256) void k_agg(const unsigned short* __restrict__ h16,
                                             const int* __restrict__ csr_src,
                                             const int* __restrict__ rowptr,
                                             const float* __restrict__ asrc,
                                             const float* __restrict__ adst,
                                             const float* __restrict__ bias,
                                             float* __restrict__ out, int N) {
    __shared__ float2 stage[4][64];   // wave-private
    int lane = threadIdx.x & 63;
    int wid = threadIdx.x >> 6;
    int node = blockIdx.x * 4 + wid;
    if (node >= N) return;
    int half = lane >> 5;
    int ch2 = (lane & 31) * 2;

    float aD = adst[node];
    // analytic self loop (counted in half 0 only; esum handles it separately)
    float a = aD + asrc[node];
    a = a > 0.f ? a : NEG_SLOPE * a;
    float w_self = __expf(a);
    unsigned hv = *(const unsigned*)&h16[(size_t)node * OUT_CH + ch2];
    float wse = half ? 0.f : w_self;
    float accx = wse * __uint_as_float(hv << 16);
    float accy = wse * __uint_as_float(hv & 0xFFFF0000u);
    float esum_lane = 0.f;

    int b0 = rowptr[node], b1 = rowptr[node + 1];
    for (int base = b0; base < b1; base += 64) {
        int idx = base + lane;
        int sv = 0;
        float wv = 0.f;
        if (idx < b1) {
            sv = csr_src[idx];                     // coalesced
            float av = aD + asrc[sv];              // parallel gather (L2-hot)
            av = av > 0.f ? av : NEG_SLOPE * av;
            wv = __expf(av);                       // once per edge
        }
        esum_lane += wv;
        stage[wid][lane] = make_float2(__int_as_float(sv), wv);

        int n = min(64, b1 - base);
        for (int j = 0; j < n; j += 8) {
#pragma unroll
            for (int k = 0; k < 4; k++) {
                float2 p = stage[wid][j + 2 * k + half];   // 2-addr broadcast, free
                int s = __float_as_int(p.x);
                unsigned v = *(const unsigned*)&h16[((size_t)s << 6) + ch2];
                accx = fmaf(p.y, __uint_as_float(v << 16), accx);
                accy = fmaf(p.y, __uint_as_float(v & 0xFFFF0000u), accy);
            }
        }
    }
    // combine half-waves (even rows in lanes 0-31, odd rows in 32-63)
    accx += __shfl_xor(accx, 32, 64);
    accy += __shfl_xor(accy, 32, 64);
#pragma unroll
    for (int m = 32; m >= 1; m >>= 1) esum_lane += __shfl_xor(esum_lane, m, 64);
    float esum = esum_lane + w_self;

    float inv = 1.f / (esum + 1e-16f);
    float2 bv = *(const float2*)&bias[ch2];
    float vx = accx * inv + bv.x;
    float vy = accy * inv + bv.y;
    float ss = vx * vx + vy * vy;
#pragma unroll
    for (int m = 16; m >= 1; m >>= 1) ss += __shfl_xor(ss, m, 64);   // within half
    float rinv = 1.f / fmaxf(sqrtf(ss), 1e-12f);
    if (!half)
        *(float2*)&out[(size_t)node * OUT_CH + ch2] = make_float2(vx * rinv, vy * rinv);
}

extern "C" void kernel_launch(void* const* d_in, const int* in_sizes, int n_in,
                              void* d_out, int out_size, void* d_ws, size_t ws_size,
                              hipStream_t stream) {
    const float* x    = (const float*)d_in[0];
    const void*  edges = d_in[1];
    const float* W    = (const float*)d_in[2];
    const float* att  = (const float*)d_in[3];
    const float* bias = (const float*)d_in[4];
    float* out = (float*)d_out;

    const int N = in_sizes[0] / IN_CH;
    const int E = in_sizes[1] / 2;
    const int NB = (N + 1023) / 1024;          // scan blocks (<=256 supported)
    const int MMB = (N + 63) / 64;             // mm blocks
    const int CNTB = ((E + 1) / 2 + 255) / 256; // count blocks (2 edges/thread)

    char* ws = (char*)d_ws;
    size_t off = 0;
    auto alloc = [&](size_t bytes) -> void* {
        void* p = ws + off;
        off += bytes;
        off = (off + 255) & ~(size_t)255;
        return p;
    };
    int*            counts   = (int*)alloc((size_t)N * 4);
    int*            rowptr   = (int*)alloc((size_t)(N + 1) * 4);
    unsigned short* rank     = (unsigned short*)alloc((size_t)E * 2);
    int*            partials = (int*)alloc((size_t)256 * 4);
    unsigned short* h16      = (unsigned short*)alloc((size_t)N * OUT_CH * 2);
    float*          asrc     = (float*)alloc((size_t)N * 4);
    float*          adst     = (float*)alloc((size_t)N * 4);
    int*            csr_src  = (int*)alloc((size_t)E * 4);

    k_init<<<(N + 255) / 256, 256, 0, stream>>>(counts, N);
    k_mm_count<<<MMB + CNTB, 256, 0, stream>>>(x, W, att, h16, asrc, adst, N,
                                               edges, counts, rank, E, MMB);
    k_scanA<<<NB, 256, 0, stream>>>(counts, partials, N);
    k_scanC<<<NB, 256, 0, stream>>>(counts, partials, NB, E, rowptr, N);
    k_scatter<<<((E + 1) / 2 + 255) / 256, 256, 0, stream>>>(edges, rank, rowptr,
                                                             csr_src, E);
    k_agg<<<(N + 3) / 4, 256, 0, stream>>>(h16, csr_src, rowptr, asrc, adst,
                                           bias, out, N);
}